// Round 7
// baseline (296.951 us; speedup 1.0000x reference)
//
#include <hip/hip_runtime.h>

typedef __attribute__((ext_vector_type(8))) short short8;
typedef __attribute__((ext_vector_type(4))) float f32x4;

#define MFMA16(a, b, c) __builtin_amdgcn_mfma_f32_16x16x32_bf16(a, b, c, 0, 0, 0)

// B=4, S=2048, D=1024, H=16, HD=64
#define SEQ 2048
#define DIM 1024
#define NH 16
#define HD 64
#define LOG2E 1.4426950408889634f

__device__ __forceinline__ ushort f2bf(float f) {
  union { float f; unsigned u; } v; v.f = f;
  unsigned r = (v.u + 0x7FFFu + ((v.u >> 16) & 1u)) >> 16;
  return (ushort)r;
}

// 1-instruction bf16 round (RNE) via packed convert
__device__ __forceinline__ ushort bf1(float f) {
  unsigned r;
  asm("v_cvt_pk_bf16_f32 %0, %1, %2" : "=v"(r) : "v"(f), "v"(f));
  return (ushort)(r & 0xffffu);
}

__device__ __forceinline__ float exp2fn(float x) {
#if __has_builtin(__builtin_amdgcn_exp2f)
  return __builtin_amdgcn_exp2f(x);
#else
  return exp2f(x);
#endif
}

// async global->LDS, 16B per lane; LDS dest = wave-uniform base + lane*16
typedef __attribute__((address_space(3))) unsigned lds_u32_t;
typedef __attribute__((address_space(1))) const unsigned glob_u32_t;
__device__ __forceinline__ void gll16(const ushort* g, ushort* l) {
  __builtin_amdgcn_global_load_lds((glob_u32_t*)g, (lds_u32_t*)l, 16, 0, 0);
}

// ---------------- prep: a{q,k,v} = bf16(inputs + pos_emb) ----------------
__global__ __launch_bounds__(256) void prep_a(
    const float* __restrict__ x, const float* __restrict__ pq,
    const float* __restrict__ pk, const float* __restrict__ pv,
    ushort* __restrict__ aq, ushort* __restrict__ ak, ushort* __restrict__ av) {
  int i = (blockIdx.x * 256 + threadIdx.x) * 4;
  int pi = i & (SEQ * DIM - 1);
  float4 xv = *(const float4*)(x + i);
  float4 q4 = *(const float4*)(pq + pi);
  float4 k4 = *(const float4*)(pk + pi);
  float4 v4 = *(const float4*)(pv + pi);
  ushort4 o;
  o.x = f2bf(xv.x + q4.x); o.y = f2bf(xv.y + q4.y);
  o.z = f2bf(xv.z + q4.z); o.w = f2bf(xv.w + q4.w);
  *(ushort4*)(aq + i) = o;
  o.x = f2bf(xv.x + k4.x); o.y = f2bf(xv.y + k4.y);
  o.z = f2bf(xv.z + k4.z); o.w = f2bf(xv.w + k4.w);
  *(ushort4*)(ak + i) = o;
  o.x = f2bf(xv.x + v4.x); o.y = f2bf(xv.y + v4.y);
  o.z = f2bf(xv.z + v4.z); o.w = f2bf(xv.w + v4.w);
  *(ushort4*)(av + i) = o;
}

// ---------------- prep: W [K=1024][N=1024] fp32 -> Wt [N][K] bf16 ----------------
__global__ __launch_bounds__(256) void transpose_w(
    const float* __restrict__ src, ushort* __restrict__ dst) {
  __shared__ float t[32][33];
  int tx = threadIdx.x & 31, ty = threadIdx.x >> 5;
  int x0 = blockIdx.x * 32, y0 = blockIdx.y * 32;
#pragma unroll
  for (int j = 0; j < 32; j += 8) t[ty + j][tx] = src[(size_t)(y0 + ty + j) * DIM + x0 + tx];
  __syncthreads();
#pragma unroll
  for (int j = 0; j < 32; j += 8)
    dst[(size_t)(x0 + ty + j) * DIM + y0 + tx] = f2bf(t[tx][ty + j]);
}

// ---------------- GEMM: C[8192x1024] = A[8192x1024] * Bt[1024x1024]^T ----------------
// global_load_lds width-16 staging, linear [128][32] LDS, double-buffered,
// ONE barrier per K-step (barrier's vmcnt drain covers the prefetch landing).
// MODE 0: out bf16 scattered to [B,H,S,HD], value = (acc+bias)*scale
// MODE 1: out fp32 row-major [8192x1024], value = acc+bias
// MODE 2: out bf16 scattered to [B,H,HD,S] (V transposed), value = acc+bias
template <int MODE>
__global__ __launch_bounds__(256) void gemm128(
    const ushort* __restrict__ A, const ushort* __restrict__ Bt,
    const float* __restrict__ bias, void* __restrict__ outp, float scale) {
  constexpr int K = 1024;
  constexpr int NIT = K / 32;
  __shared__ __align__(16) ushort As[2][128 * 32];
  __shared__ __align__(16) ushort Bs[2][128 * 32];
  const int tid = threadIdx.x;
  const int wave = tid >> 6, lane = tid & 63;
  const int wr = wave >> 1, wc = wave & 1;
  const int g = lane >> 4, l15 = lane & 15;
  const int bm = blockIdx.x, bn = blockIdx.y;

  // staging chunk ids (16B chunks; 4 chunks/row): c0 covers rows 0..63, c1 rows 64..127
  const int c0 = wave * 64 + lane, c1 = c0 + 256;
  const ushort* gA0 = A + (size_t)(bm * 128 + (c0 >> 2)) * K + (c0 & 3) * 8;
  const ushort* gA1 = A + (size_t)(bm * 128 + (c1 >> 2)) * K + (c1 & 3) * 8;
  const ushort* gB0 = Bt + (size_t)(bn * 128 + (c0 >> 2)) * K + (c0 & 3) * 8;
  const ushort* gB1 = Bt + (size_t)(bn * 128 + (c1 >> 2)) * K + (c1 & 3) * 8;
  const int lofs0 = wave * 512;         // ushort units (chunk*8), wave-uniform
  const int lofs1 = 2048 + wave * 512;

  f32x4 acc[4][4] = {};

  // prologue: stage tile 0 into buf 0
  gll16(gA0, &As[0][lofs0]);
  gll16(gA1, &As[0][lofs1]);
  gll16(gB0, &Bs[0][lofs0]);
  gll16(gB1, &Bs[0][lofs1]);
  __syncthreads();

  for (int it = 0; it < NIT; ++it) {
    const int cur = it & 1, nxt = cur ^ 1;
    if (it + 1 < NIT) {
      const int ko = (it + 1) * 32;
      gll16(gA0 + ko, &As[nxt][lofs0]);
      gll16(gA1 + ko, &As[nxt][lofs1]);
      gll16(gB0 + ko, &Bs[nxt][lofs0]);
      gll16(gB1 + ko, &Bs[nxt][lofs1]);
    }
    short8 af[4], bfr[4];
#pragma unroll
    for (int m = 0; m < 4; ++m)
      af[m] = *(const short8*)&As[cur][(wr * 64 + m * 16 + l15) * 32 + g * 8];
#pragma unroll
    for (int n = 0; n < 4; ++n)
      bfr[n] = *(const short8*)&Bs[cur][(wc * 64 + n * 16 + l15) * 32 + g * 8];
#pragma unroll
    for (int m = 0; m < 4; ++m)
#pragma unroll
      for (int n = 0; n < 4; ++n) acc[m][n] = MFMA16(af[m], bfr[n], acc[m][n]);
    __syncthreads();  // drains my lgkm reads + my gll vmcnt, then barrier
  }

#pragma unroll
  for (int m = 0; m < 4; ++m) {
    int row = bm * 128 + wr * 64 + m * 16 + g * 4;
#pragma unroll
    for (int n = 0; n < 4; ++n) {
      int col = bn * 128 + wc * 64 + n * 16 + l15;
      float bv = bias[col];
#pragma unroll
      for (int j = 0; j < 4; ++j) {
        float v = (acc[m][n][j] + bv) * scale;
        int r = row + j;
        if (MODE == 0) {
          int b = r >> 11, s = r & (SEQ - 1), h = col >> 6, hd = col & (HD - 1);
          ((ushort*)outp)[((size_t)((b * NH + h) * SEQ + s)) * HD + hd] = f2bf(v);
        } else if (MODE == 2) {
          int b = r >> 11, s = r & (SEQ - 1), h = col >> 6, hd = col & (HD - 1);
          ((ushort*)outp)[((size_t)((b * NH + h) * HD + hd)) * SEQ + s] = f2bf(v);
        } else {
          ((float*)outp)[(size_t)r * DIM + col] = v;
        }
      }
    }
  }
}

// ---------------- flash attention v5 (round-5 verified, fastest passing) ----
// grid 1024 = 16 q-tiles x 64 bh (XCD-swizzled). 4 waves; each wave owns 32 q-rows
// (2 subtiles of 16). Q as A-operand, K as B-operand. No-max exp2 softmax.
__global__ __launch_bounds__(256) void attn5(
    const ushort* __restrict__ Q, const ushort* __restrict__ K,
    const ushort* __restrict__ VT, const float* __restrict__ abias,
    const float* __restrict__ kvbias, ushort* __restrict__ X) {
  constexpr int LDK = 72, LDV = 72, LDP = 72;
  __shared__ __align__(16) ushort Ks[64 * LDK];      // [key][d]
  __shared__ __align__(16) ushort Vs[64 * LDV];      // [d][key]  (V^T tile)
  __shared__ __align__(16) ushort Ps[4][32 * LDP];   // per-wave [q_local][key]
  const int tid = threadIdx.x;
  const int w = tid >> 6, lane = tid & 63, g = lane >> 4, l15 = lane & 15;
  const int px = blockIdx.x;
  const int qt = (px & 7) | ((px >> 9) << 3);   // bijective XCD swizzle
  const int bh = (px >> 3) & 63;
  const int b = bh >> 4, h = bh & (NH - 1);
  const int q0 = qt * 128;

  // Q fragments as A-operand: row = l15, k = c*32 + g*8 (+i)
  short8 qf[2][2];
#pragma unroll
  for (int sub = 0; sub < 2; ++sub) {
    const ushort* qp = Q + ((size_t)bh * SEQ + q0 + w * 32 + sub * 16 + l15) * HD;
#pragma unroll
    for (int c = 0; c < 2; ++c) qf[sub][c] = *(const short8*)(qp + c * 32 + g * 8);
  }

  f32x4 o[2][4] = {};
  float l_lane[2][4] = {};

  const int sr = tid >> 2, scc = (tid & 3) * 16;
  const ushort* Kp = K + (size_t)bh * SEQ * HD;    // [key][d]
  const ushort* Vp = VT + (size_t)bh * HD * SEQ;   // [d][key]
  const float* abp = abias + (size_t)q0 * SEQ;
  const float* kvp = kvbias + b * SEQ;

  // prologue: tile 0 into regs
  uint4 ka = *(const uint4*)(Kp + (size_t)sr * HD + scc);
  uint4 kb = *(const uint4*)(Kp + (size_t)sr * HD + scc + 8);
  uint4 va = *(const uint4*)(Vp + (size_t)sr * SEQ + scc);
  uint4 vb = *(const uint4*)(Vp + (size_t)sr * SEQ + scc + 8);

  for (int kt = 0; kt < SEQ / 64; ++kt) {
    const int k0 = kt * 64;
    __syncthreads();  // previous tile's LDS reads complete
    *(uint4*)&Ks[sr * LDK + scc] = ka;
    *(uint4*)&Ks[sr * LDK + scc + 8] = kb;
    *(uint4*)&Vs[sr * LDV + scc] = va;
    *(uint4*)&Vs[sr * LDV + scc + 8] = vb;
    __syncthreads();

    // issue this tile's bias loads EARLY (latency hides under QK MFMAs)
    float bkv[4];
#pragma unroll
    for (int ct = 0; ct < 4; ++ct) bkv[ct] = kvp[k0 + ct * 16 + l15];
    float abf[2][4][4];
#pragma unroll
    for (int sub = 0; sub < 2; ++sub)
#pragma unroll
      for (int j = 0; j < 4; ++j) {
        const float* abr = abp + (size_t)(w * 32 + sub * 16 + 4 * g + j) * SEQ + k0 + l15;
#pragma unroll
        for (int ct = 0; ct < 4; ++ct) abf[sub][ct][j] = abr[ct * 16];
      }

    // prefetch next tile into regs (overlaps all of this tile's compute)
    if (kt + 1 < SEQ / 64) {
      ka = *(const uint4*)(Kp + (size_t)(k0 + 64 + sr) * HD + scc);
      kb = *(const uint4*)(Kp + (size_t)(k0 + 64 + sr) * HD + scc + 8);
      va = *(const uint4*)(Vp + (size_t)sr * SEQ + k0 + 64 + scc);
      vb = *(const uint4*)(Vp + (size_t)sr * SEQ + k0 + 64 + scc + 8);
    }

    // S = Q K^T : rows q (D: 4g+j), cols key (D: l15). 2 subtiles x 4 key-chunks.
    f32x4 s4[2][4];
#pragma unroll
    for (int ct = 0; ct < 4; ++ct) {
      short8 kf0 = *(const short8*)&Ks[(ct * 16 + l15) * LDK + g * 8];
      short8 kf1 = *(const short8*)&Ks[(ct * 16 + l15) * LDK + 32 + g * 8];
#pragma unroll
      for (int sub = 0; sub < 2; ++sub) {
        f32x4 z = {0.f, 0.f, 0.f, 0.f};
        f32x4 t = MFMA16(qf[sub][0], kf0, z);
        s4[sub][ct] = MFMA16(qf[sub][1], kf1, t);
      }
    }

    // no-max softmax in exp2 domain; per-lane l partials (no in-loop reductions)
#pragma unroll
    for (int sub = 0; sub < 2; ++sub) {
      float p[4][4];
#pragma unroll
      for (int ct = 0; ct < 4; ++ct)
#pragma unroll
        for (int j = 0; j < 4; ++j)
          p[ct][j] = exp2fn(fmaf(abf[sub][ct][j] + bkv[ct], LOG2E, s4[sub][ct][j]));
#pragma unroll
      for (int j = 0; j < 4; ++j)
        l_lane[sub][j] += (p[0][j] + p[1][j]) + (p[2][j] + p[3][j]);
#pragma unroll
      for (int ct = 0; ct < 4; ++ct)
#pragma unroll
        for (int j = 0; j < 4; ++j)
          Ps[w][(sub * 16 + 4 * g + j) * LDP + ct * 16 + l15] = bf1(p[ct][j]);
    }

    // wave-private P ready
    asm volatile("s_waitcnt lgkmcnt(0)" ::: "memory");
    __builtin_amdgcn_sched_barrier(0);

    // O += P V  (P as A: row=l15 within sub-block; V^T as B: col=l15=d)
    short8 pa[2][2];
#pragma unroll
    for (int sub = 0; sub < 2; ++sub)
#pragma unroll
      for (int ks = 0; ks < 2; ++ks)
        pa[sub][ks] = *(const short8*)&Ps[w][(sub * 16 + l15) * LDP + ks * 32 + g * 8];
#pragma unroll
    for (int ctd = 0; ctd < 4; ++ctd) {
      short8 vf0 = *(const short8*)&Vs[(ctd * 16 + l15) * LDV + g * 8];
      short8 vf1 = *(const short8*)&Vs[(ctd * 16 + l15) * LDV + 32 + g * 8];
#pragma unroll
      for (int sub = 0; sub < 2; ++sub) {
        o[sub][ctd] = MFMA16(pa[sub][0], vf0, o[sub][ctd]);
        o[sub][ctd] = MFMA16(pa[sub][1], vf1, o[sub][ctd]);
      }
    }
  }

  // one final l reduction per row (16-lane l15 group), then normalize + write
#pragma unroll
  for (int sub = 0; sub < 2; ++sub) {
    float inv[4];
#pragma unroll
    for (int j = 0; j < 4; ++j) {
      float l = l_lane[sub][j];
      l += __shfl_xor(l, 1);
      l += __shfl_xor(l, 2);
      l += __shfl_xor(l, 4);
      l += __shfl_xor(l, 8);
      inv[j] = 1.0f / l;
    }
#pragma unroll
    for (int ctd = 0; ctd < 4; ++ctd)
#pragma unroll
      for (int j = 0; j < 4; ++j) {
        size_t row = (size_t)b * SEQ + q0 + w * 32 + sub * 16 + 4 * g + j;
        X[row * DIM + h * HD + ctd * 16 + l15] = bf1(o[sub][ctd][j] * inv[j]);
      }
  }
}

extern "C" void kernel_launch(void* const* d_in, const int* in_sizes, int n_in,
                              void* d_out, int out_size, void* d_ws, size_t ws_size,
                              hipStream_t stream) {
  const float* inputs_q = (const float*)d_in[0];
  const float* pos_q = (const float*)d_in[1];
  const float* pos_k = (const float*)d_in[2];
  const float* pos_v = (const float*)d_in[3];
  const float* abias = (const float*)d_in[4];
  const float* kvbias = (const float*)d_in[5];
  const float* wq = (const float*)d_in[6];
  const float* bq = (const float*)d_in[7];
  const float* wk = (const float*)d_in[8];
  const float* bk = (const float*)d_in[9];
  const float* wv = (const float*)d_in[10];
  const float* bv = (const float*)d_in[11];
  const float* wo = (const float*)d_in[12];
  const float* bo = (const float*)d_in[13];

  char* ws = (char*)d_ws;
  const size_t MB = 1ull << 20;
  ushort* wqT = (ushort*)(ws + 0 * MB);
  ushort* wkT = (ushort*)(ws + 2 * MB);
  ushort* wvT = (ushort*)(ws + 4 * MB);
  ushort* woT = (ushort*)(ws + 6 * MB);
  ushort* aq = (ushort*)(ws + 8 * MB);
  ushort* ak = (ushort*)(ws + 24 * MB);
  ushort* av = (ushort*)(ws + 40 * MB);
  ushort* Qb = (ushort*)(ws + 56 * MB);
  ushort* Kb = (ushort*)(ws + 72 * MB);
  ushort* VTb = (ushort*)(ws + 88 * MB);
  ushort* Xb = (ushort*)(ws + 8 * MB);  // alias aq (dead after Q-GEMM)

  prep_a<<<8192, 256, 0, stream>>>(inputs_q, pos_q, pos_k, pos_v, aq, ak, av);
  dim3 tg(32, 32);
  transpose_w<<<tg, 256, 0, stream>>>(wq, wqT);
  transpose_w<<<tg, 256, 0, stream>>>(wk, wkT);
  transpose_w<<<tg, 256, 0, stream>>>(wv, wvT);
  transpose_w<<<tg, 256, 0, stream>>>(wo, woT);
  dim3 gg(64, 8);
  // Q pre-scaled by 1/sqrt(64) * log2(e): softmax runs in exp2 domain
  gemm128<0><<<gg, 256, 0, stream>>>(aq, wqT, bq, Qb, 0.125f * LOG2E);
  gemm128<0><<<gg, 256, 0, stream>>>(ak, wkT, bk, Kb, 1.0f);
  gemm128<2><<<gg, 256, 0, stream>>>(av, wvT, bv, VTb, 1.0f);
  attn5<<<1024, 256, 0, stream>>>(Qb, Kb, VTb, abias, kvbias, Xb);
  gemm128<1><<<gg, 256, 0, stream>>>(Xb, woT, bo, d_out, 1.0f);
}